// Round 1
// baseline (290.697 us; speedup 1.0000x reference)
//
#include <hip/hip_runtime.h>
#include <stdint.h>

// SoftALU: inputs are EXACT one-hot byte encodings; all softmax(100*x) ops
// collapse to hard integer ALU (cold probs ~ exp(-100) ~= 3.7e-44 ~ 0).
// So: decode uint32 a,b per batch, compute {add,sub,mul,div,and,or,xor},
// write one-hot f32 outputs. Pure streaming-write kernel (~224 MiB out).

__global__ __launch_bounds__(256) void softalu_kernel(const float* __restrict__ a,
                                                      const float* __restrict__ b,
                                                      float* __restrict__ out,
                                                      int B) {
    const int batch = blockIdx.x;
    const int t = threadIdx.x;

    __shared__ uint32_t sh_bytes[8];  // a byte0..3, b byte0..3 (byte n = bits 8n..8n+7)
    __shared__ uint32_t res[7];

    const float* pa = a + (size_t)batch * 1024;
    const float* pb = b + (size_t)batch * 1024;
#pragma unroll
    for (int n = 0; n < 4; ++n) {
        if (pa[n * 256 + t] > 0.5f) sh_bytes[n] = (uint32_t)t;
        if (pb[n * 256 + t] > 0.5f) sh_bytes[4 + n] = (uint32_t)t;
    }
    __syncthreads();

    if (t == 0) {
        const uint32_t av = sh_bytes[0] | (sh_bytes[1] << 8) | (sh_bytes[2] << 16) | (sh_bytes[3] << 24);
        const uint32_t bv = sh_bytes[4] | (sh_bytes[5] << 8) | (sh_bytes[6] << 16) | (sh_bytes[7] << 24);
        res[0] = av + bv;                  // soft_add(a,b)
        res[1] = av - bv;                  // soft_add(a, soft_negate(b)) = a - b mod 2^32
        res[2] = av * bv;                  // wrapping mul, matches jnp uint32
        res[3] = bv ? (av / bv) : 0u;      // div, 0 when b==0
        res[4] = av & bv;
        res[5] = av | bv;
        res[6] = av ^ bv;
    }
    __syncthreads();

    // Write one-hot rows: out[((op*B + batch)*4 + n)*256 + c].
    // Thread t: n = t/64 (byte index), lane4 = t%64 (float4 within 256-float row).
    const int n = t >> 6;
    const int lane4 = t & 63;
    const int c0 = lane4 * 4;

#pragma unroll
    for (int op = 0; op < 7; ++op) {
        const int rb = (int)((res[op] >> (8 * n)) & 255u);
        float4 v;
        v.x = (c0 + 0 == rb) ? 1.0f : 0.0f;
        v.y = (c0 + 1 == rb) ? 1.0f : 0.0f;
        v.z = (c0 + 2 == rb) ? 1.0f : 0.0f;
        v.w = (c0 + 3 == rb) ? 1.0f : 0.0f;
        float4* dst = (float4*)(out + (((size_t)op * B + batch) * 4 + n) * 256) + lane4;
        *dst = v;
    }
}

extern "C" void kernel_launch(void* const* d_in, const int* in_sizes, int n_in,
                              void* d_out, int out_size, void* d_ws, size_t ws_size,
                              hipStream_t stream) {
    const float* a = (const float*)d_in[0];
    const float* b = (const float*)d_in[1];
    float* out = (float*)d_out;
    const int B = in_sizes[0] / (4 * 256);  // 8192
    softalu_kernel<<<B, 256, 0, stream>>>(a, b, out, B);
}

// Round 3
// 286.932 us; speedup vs baseline: 1.0131x; 1.0131x over previous
//
#include <hip/hip_runtime.h>
#include <stdint.h>

// SoftALU: inputs are EXACT one-hot byte encodings; softmax(100*x) collapses
// to hard integer ALU (cold probs ~ exp(-100) ~ 0). Pipeline:
//   K1 decode: one-hot -> uint32 a,b; compute 7 results -> d_ws (229 KiB, L2-hot)
//   K2 writer: pure streaming one-hot emit, ~224 MiB, fill-kernel-shaped.
// Split so the 224 MiB store stream is never stalled on decode latency.

typedef float vfloat4 __attribute__((ext_vector_type(4)));  // native vec for nontemporal builtin

__global__ __launch_bounds__(256) void decode_kernel(const float* __restrict__ a,
                                                     const float* __restrict__ b,
                                                     uint32_t* __restrict__ res,
                                                     int B) {
    const int batch = blockIdx.x;
    const int t = threadIdx.x;

    __shared__ uint32_t sh_bytes[8];  // a byte0..3, b byte0..3 (byte n = bits 8n..8n+7)

    const float* pa = a + (size_t)batch * 1024;
    const float* pb = b + (size_t)batch * 1024;
#pragma unroll
    for (int n = 0; n < 4; ++n) {
        if (pa[n * 256 + t] > 0.5f) sh_bytes[n] = (uint32_t)t;
        if (pb[n * 256 + t] > 0.5f) sh_bytes[4 + n] = (uint32_t)t;
    }
    __syncthreads();

    if (t == 0) {
        const uint32_t av = sh_bytes[0] | (sh_bytes[1] << 8) | (sh_bytes[2] << 16) | (sh_bytes[3] << 24);
        const uint32_t bv = sh_bytes[4] | (sh_bytes[5] << 8) | (sh_bytes[6] << 16) | (sh_bytes[7] << 24);
        res[0 * B + batch] = av + bv;              // soft_add(a,b)
        res[1 * B + batch] = av - bv;              // a + negate(b) = a - b mod 2^32
        res[2 * B + batch] = av * bv;              // wrapping mul
        res[3 * B + batch] = bv ? (av / bv) : 0u;  // div, 0 when b==0
        res[4 * B + batch] = av & bv;
        res[5 * B + batch] = av | bv;
        res[6 * B + batch] = av ^ bv;
    }
}

// Output layout: out[((op*B + batch)*4 + n)*256 + c], contiguous as vfloat4[7*B*4*64].
// Each wave handles 64 consecutive float4 = exactly one 256-float row -> the
// res[] lookup is wave-uniform (scalar load), then 1 nontemporal 16B store/lane.
__global__ __launch_bounds__(256) void writer_kernel(const uint32_t* __restrict__ res,
                                                     vfloat4* __restrict__ out,
                                                     int B) {
    const size_t total = (size_t)7 * B * 4 * 64;  // vfloat4 count
    const size_t stride = (size_t)gridDim.x * blockDim.x;
    for (size_t g = (size_t)blockIdx.x * blockDim.x + threadIdx.x; g < total; g += stride) {
        const int lane4 = (int)(g & 63);
        const size_t row = g >> 6;          // (op*B + batch)*4 + n  — wave-uniform
        const int n = (int)(row & 3);
        const int ob = __builtin_amdgcn_readfirstlane((int)(row >> 2));  // force SGPR index
        const uint32_t r = res[ob];
        const int rb = (int)((r >> (8 * n)) & 255u);
        const int c0 = lane4 * 4;
        vfloat4 v;
        v.x = (c0 + 0 == rb) ? 1.0f : 0.0f;
        v.y = (c0 + 1 == rb) ? 1.0f : 0.0f;
        v.z = (c0 + 2 == rb) ? 1.0f : 0.0f;
        v.w = (c0 + 3 == rb) ? 1.0f : 0.0f;
        __builtin_nontemporal_store(v, &out[g]);
    }
}

extern "C" void kernel_launch(void* const* d_in, const int* in_sizes, int n_in,
                              void* d_out, int out_size, void* d_ws, size_t ws_size,
                              hipStream_t stream) {
    const float* a = (const float*)d_in[0];
    const float* b = (const float*)d_in[1];
    float* out = (float*)d_out;
    const int B = in_sizes[0] / (4 * 256);  // 8192
    uint32_t* res = (uint32_t*)d_ws;        // needs 7*B*4 = 229 KiB of ws

    decode_kernel<<<B, 256, 0, stream>>>(a, b, res, B);
    writer_kernel<<<4096, 256, 0, stream>>>(res, (vfloat4*)out, B);
}